// Round 6
// baseline (591.525 us; speedup 1.0000x reference)
//
#include <hip/hip_runtime.h>

// MMoE: B=16384, D=1024, E=8, H=512, T=256, TASKS=3
// R2: 701 us. R3: 593 (coalesced gates). R4: 521 (XOR-swizzle LDS, conflicts
// 2.5e7->0, GEMM1 123->84 us = 825 TF m97 plateau). R5: 498 (fused tail).
// R6: gemm2+combine fused (8-expert loop in-block, fp32 task accumulators,
//     gates via LDS) -> eoc buffer eliminated (128 MB/chunk HBM round-trip),
//     chunk cost Bc*11264 B so Bc=16384 can fit.

#define BM 128
#define BN 128
#define BK 64

typedef __attribute__((ext_vector_type(8))) short short8;
typedef __attribute__((ext_vector_type(4))) float floatx4;
typedef __attribute__((ext_vector_type(4))) unsigned short ushortx4;
typedef __attribute__((ext_vector_type(8))) unsigned short ushortx8;

__device__ __forceinline__ unsigned short f32_to_bf16(float f) {
  unsigned int u = __float_as_uint(f);
  u += 0x7fffu + ((u >> 16) & 1u);   // round-to-nearest-even (no NaNs in this net)
  return (unsigned short)(u >> 16);
}
__device__ __forceinline__ float bf16_to_f32(unsigned short h) {
  return __uint_as_float(((unsigned int)h) << 16);
}

__device__ __forceinline__ void async_cp16(const void* g, void* lds) {
  __builtin_amdgcn_global_load_lds(
      (const __attribute__((address_space(1))) void*)g,
      (__attribute__((address_space(3))) void*)lds, 16, 0, 0);
}

// ---------------- all weight prep in one kernel ----------------
__device__ __forceinline__ void transpose_slice(
    const float* __restrict__ in, unsigned short* __restrict__ out,
    int K, int N, float (*tile)[33]) {
  int n0 = blockIdx.x * 32, k0 = blockIdx.y * 32;
  for (int i = threadIdx.y; i < 32; i += 8)
    tile[i][threadIdx.x] = in[(size_t)(k0 + i) * N + n0 + threadIdx.x];
  __syncthreads();
  for (int i = threadIdx.y; i < 32; i += 8)
    out[(size_t)(n0 + i) * K + k0 + threadIdx.x] = f32_to_bf16(tile[threadIdx.x][i]);
}

__global__ void prep_kernel(const float* __restrict__ We1, const float* __restrict__ We2,
                            const float* __restrict__ Wt1, const float* __restrict__ Wg,
                            unsigned short* __restrict__ W1T, unsigned short* __restrict__ W2T,
                            unsigned short* __restrict__ Wt1T, float* __restrict__ WgT) {
  __shared__ float tile[32][33];
  int z = blockIdx.z;
  if (z < 8) {
    transpose_slice(We1 + (size_t)z * 524288, W1T + (size_t)z * 524288, 1024, 512, tile);
  } else if (z < 16) {
    if (blockIdx.y < 16)
      transpose_slice(We2 + (size_t)(z - 8) * 262144, W2T + (size_t)(z - 8) * 262144, 512, 512, tile);
  } else if (z < 19) {
    if (blockIdx.x < 8 && blockIdx.y < 16)
      transpose_slice(Wt1 + (size_t)(z - 16) * 131072, Wt1T + (size_t)(z - 16) * 131072, 512, 256, tile);
  } else {
    if (blockIdx.x < 16 && blockIdx.y < 6) {
      int idx = (blockIdx.y * 16 + blockIdx.x) * 256 + threadIdx.y * 32 + threadIdx.x;
      int t = idx >> 13, r = idx & 8191, e = r >> 10, d = r & 1023;
      WgT[idx] = Wg[t * 8192 + d * 8 + e];
    }
  }
}

// ---------------- gates + x->bf16 (fused; reads x once) ----------------
__global__ __launch_bounds__(256) void gates_cvt_kernel(
    const float* __restrict__ x, const float* __restrict__ WgT,
    const float* __restrict__ bg, float* __restrict__ gout,
    unsigned short* __restrict__ xb) {
  int wave = threadIdx.x >> 6, lane = threadIdx.x & 63;
  int b = blockIdx.x * 4 + wave;
  const float* xr = x + (size_t)b * 1024;
  float xv[16];
#pragma unroll
  for (int j = 0; j < 16; j++) xv[j] = xr[lane + 64 * j];
  unsigned short* xbr = xb + (size_t)b * 1024;
#pragma unroll
  for (int j = 0; j < 16; j++) xbr[lane + 64 * j] = f32_to_bf16(xv[j]);
  float mylogit = 0.f;
#pragma unroll
  for (int te = 0; te < 24; te++) {
    const float* w = WgT + te * 1024;
    float a = 0.f;
#pragma unroll
    for (int j = 0; j < 16; j++) a += xv[j] * w[lane + 64 * j];
#pragma unroll
    for (int off = 32; off > 0; off >>= 1) a += __shfl_xor(a, off, 64);
    if (lane == te) mylogit = a;
  }
  if (lane < 24) {
    int t = lane >> 3, e = lane & 7;
    float logit = mylogit + bg[lane];
    float m = logit;
    m = fmaxf(m, __shfl_xor(m, 4, 64));
    m = fmaxf(m, __shfl_xor(m, 2, 64));
    m = fmaxf(m, __shfl_xor(m, 1, 64));
    float ex = __expf(logit - m);
    float s = ex;
    s += __shfl_xor(s, 4, 64);
    s += __shfl_xor(s, 2, 64);
    s += __shfl_xor(s, 1, 64);
    gout[(size_t)t * 131072 + (size_t)b * 8 + e] = ex / s;
  }
}

// ---------------- m97-style bf16 GEMM: C = relu(A * B^T + bias), bf16 out ----------------
// Used for GEMM1 only. LDS XOR-swizzled (R4).
__global__ __launch_bounds__(256) void gemm_bt_relu(
    const unsigned short* __restrict__ Abase, long aOffZ, int lda,
    const unsigned short* __restrict__ Bbase, long bOffZ,
    const float* __restrict__ biasBase, int biasOffZ,
    unsigned short* __restrict__ Cbase, long cOffZ, int ldc,
    int K) {
  __shared__ __align__(16) unsigned short As[BM * BK];
  __shared__ __align__(16) unsigned short Bs[BN * BK];
  const int tid = threadIdx.x;
  const int z = blockIdx.z;
  const unsigned short* A = Abase + (size_t)aOffZ * z + (size_t)blockIdx.x * BM * lda;
  const unsigned short* Bt = Bbase + (size_t)bOffZ * z + (size_t)blockIdx.y * BN * K;
  const float* bias = biasBase + (size_t)biasOffZ * z + blockIdx.y * BN;
  unsigned short* C = Cbase + (size_t)cOffZ * z + (size_t)blockIdx.x * BM * ldc + blockIdx.y * BN;

  const int wave = tid >> 6, lane = tid & 63;
  const int wm = (wave >> 1) * 64, wn = (wave & 1) * 64;
  const int lm = lane & 15, lq = lane >> 4;
  const int sw = lm & 7;

  floatx4 acc[4][4] = {};

  const int sr = tid >> 3;
  const int sc = (((tid & 7) ^ (sr & 7)) << 3);

  for (int kt = 0; kt < K; kt += BK) {
#pragma unroll
    for (int i = 0; i < 4; i++)
      async_cp16(A + (size_t)(sr + 32 * i) * lda + kt + sc,
                 (char*)As + i * 4096 + tid * 16);
#pragma unroll
    for (int i = 0; i < 4; i++)
      async_cp16(Bt + (size_t)(sr + 32 * i) * K + kt + sc,
                 (char*)Bs + i * 4096 + tid * 16);
    __syncthreads();
#pragma unroll
    for (int ks = 0; ks < 2; ks++) {
      short8 af[4], bf[4];
      const int ch = ((ks * 4 + lq) ^ sw) << 3;
#pragma unroll
      for (int i = 0; i < 4; i++)
        af[i] = *(const short8*)(As + (wm + 16 * i + lm) * BK + ch);
#pragma unroll
      for (int j = 0; j < 4; j++)
        bf[j] = *(const short8*)(Bs + (wn + 16 * j + lm) * BK + ch);
#pragma unroll
      for (int i = 0; i < 4; i++)
#pragma unroll
        for (int j = 0; j < 4; j++)
          acc[i][j] = __builtin_amdgcn_mfma_f32_16x16x32_bf16(af[i], bf[j], acc[i][j], 0, 0, 0);
    }
    __syncthreads();
  }

#pragma unroll
  for (int i = 0; i < 4; i++) {
    const int row = wm + 16 * i + lq * 4;
#pragma unroll
    for (int j = 0; j < 4; j++) {
      const int col = wn + 16 * j + lm;
      const float bv = bias[col];
#pragma unroll
      for (int v = 0; v < 4; v++) {
        float val = fmaxf(acc[i][j][v] + bv, 0.0f);
        C[(size_t)(row + v) * ldc + col] = f32_to_bf16(val);
      }
    }
  }
}

// ---------------- fused GEMM2 + combine ----------------
// tic[t, m0+row, n0+col] = sum_e g[t,b0+m0+row,e] * relu(h1[row] @ We2[e] + be2[e])
// Block 256 thr (4 waves), tile 128x64, wave tile 64x32; 8-expert loop inside.
// Gates pre-staged to LDS as [t][e][128] so 4 rows = one ds_read_b128.
__global__ __launch_bounds__(256) void gemm2_combine_kernel(
    const unsigned short* __restrict__ h1,   // [Bc][8][512], row stride 4096
    const unsigned short* __restrict__ W2T,  // [8][512][512] (e,n,k)
    const float* __restrict__ be2,           // [8][512]
    const float* __restrict__ gts,           // [3][16384][8]
    unsigned short* __restrict__ tic,        // [3][Bc][512]
    int b0, int Bc) {
  __shared__ __align__(16) unsigned short As[128 * 64];  // 16 KB
  __shared__ __align__(16) unsigned short Bs[64 * 64];   //  8 KB
  __shared__ float gds[3072];                            // 12 KB [t][e][128]
  const int tid = threadIdx.x;
  const int m0 = blockIdx.x * 128, n0 = blockIdx.y * 64;
  const int wave = tid >> 6, lane = tid & 63;
  const int wm = (wave >> 1) * 64, wn = (wave & 1) * 32;
  const int lm = lane & 15, lq = lane >> 4;
  const int sw = lm & 7;
  const int sr = tid >> 3;
  const int sc = (((tid & 7) ^ (sr & 7)) << 3);

  // stage gates (consumed only after >=2 barriers; lgkmcnt drained by them)
#pragma unroll
  for (int q = 0; q < 12; q++) {
    int idx = tid + 256 * q;
    int t = idx >> 10, e = (idx >> 7) & 7, r = idx & 127;
    gds[idx] = gts[((size_t)t * 16384 + b0 + m0 + r) * 8 + e];
  }

  floatx4 tacc[3][4][2] = {};

  for (int e = 0; e < 8; e++) {
    floatx4 acc[4][2] = {};
    const unsigned short* A = h1 + (size_t)m0 * 4096 + e * 512;
    const unsigned short* Bt = W2T + (size_t)e * 262144 + (size_t)n0 * 512;
    for (int kt = 0; kt < 512; kt += 64) {
#pragma unroll
      for (int i = 0; i < 4; i++)
        async_cp16(A + (size_t)(sr + 32 * i) * 4096 + kt + sc,
                   (char*)As + i * 4096 + tid * 16);
#pragma unroll
      for (int i = 0; i < 2; i++)
        async_cp16(Bt + (size_t)(sr + 32 * i) * 512 + kt + sc,
                   (char*)Bs + i * 4096 + tid * 16);
      __syncthreads();
#pragma unroll
      for (int ks = 0; ks < 2; ks++) {
        short8 af[4], bf[2];
        const int ch = ((ks * 4 + lq) ^ sw) << 3;
#pragma unroll
        for (int i = 0; i < 4; i++)
          af[i] = *(const short8*)(As + (wm + 16 * i + lm) * 64 + ch);
#pragma unroll
        for (int j = 0; j < 2; j++)
          bf[j] = *(const short8*)(Bs + (wn + 16 * j + lm) * 64 + ch);
#pragma unroll
        for (int i = 0; i < 4; i++)
#pragma unroll
          for (int j = 0; j < 2; j++)
            acc[i][j] = __builtin_amdgcn_mfma_f32_16x16x32_bf16(af[i], bf[j], acc[i][j], 0, 0, 0);
      }
      __syncthreads();
    }
    // per-expert epilogue: gated accumulate (reads only regs + gds)
    float b2v[2];
#pragma unroll
    for (int j = 0; j < 2; j++) b2v[j] = be2[e * 512 + n0 + wn + 16 * j + lm];
#pragma unroll
    for (int i = 0; i < 4; i++) {
      floatx4 gv[3];
#pragma unroll
      for (int t = 0; t < 3; t++)
        gv[t] = *(const floatx4*)(gds + t * 1024 + e * 128 + wm + 16 * i + lq * 4);
#pragma unroll
      for (int j = 0; j < 2; j++)
#pragma unroll
        for (int v = 0; v < 4; v++) {
          float val = fmaxf(acc[i][j][v] + b2v[j], 0.0f);
#pragma unroll
          for (int t = 0; t < 3; t++) tacc[t][i][j][v] += gv[t][v] * val;
        }
    }
  }

#pragma unroll
  for (int t = 0; t < 3; t++)
#pragma unroll
    for (int i = 0; i < 4; i++)
#pragma unroll
      for (int j = 0; j < 2; j++)
#pragma unroll
        for (int v = 0; v < 4; v++) {
          int row = wm + 16 * i + lq * 4 + v;
          int col = wn + 16 * j + lm;
          tic[((size_t)t * Bc + m0 + row) * 512 + n0 + col] = f32_to_bf16(tacc[t][i][j][v]);
        }
}

// ---------------- fused towers: preds = sigmoid(relu(tic @ Wt1 + bt1) . Wt2 + bt2) ----------------
__global__ __launch_bounds__(512) void tower_fused_kernel(
    const unsigned short* __restrict__ tic, const unsigned short* __restrict__ Wt1T,
    const float* __restrict__ bt1, const float* __restrict__ Wt2,
    const float* __restrict__ bt2, float* __restrict__ out,
    int b0, int Bc) {
  __shared__ __align__(16) unsigned short As[128 * 64];
  __shared__ __align__(16) unsigned short Bs[256 * 64];
  const int tid = threadIdx.x;
  const int mtiles = Bc >> 7;
  const int t = blockIdx.x / mtiles;
  const int xbl = blockIdx.x % mtiles;
  const unsigned short* A = tic + ((size_t)t * Bc + (size_t)xbl * 128) * 512;
  const unsigned short* Bt = Wt1T + (size_t)t * 131072;

  const int wave = tid >> 6, lane = tid & 63;
  const int wm = (wave >> 2) * 64, wn = (wave & 3) * 64;
  const int lm = lane & 15, lq = lane >> 4;
  const int sw = lm & 7;

  floatx4 acc[4][4] = {};

  const int sr = tid >> 3;
  const int sc = (((tid & 7) ^ (sr & 7)) << 3);

  for (int kt = 0; kt < 512; kt += 64) {
#pragma unroll
    for (int i = 0; i < 2; i++)
      async_cp16(A + (size_t)(sr + 64 * i) * 512 + kt + sc,
                 (char*)As + i * 8192 + tid * 16);
#pragma unroll
    for (int i = 0; i < 4; i++)
      async_cp16(Bt + (size_t)(sr + 64 * i) * 512 + kt + sc,
                 (char*)Bs + i * 8192 + tid * 16);
    __syncthreads();
#pragma unroll
    for (int ks = 0; ks < 2; ks++) {
      short8 af[4], bf[4];
      const int ch = ((ks * 4 + lq) ^ sw) << 3;
#pragma unroll
      for (int i = 0; i < 4; i++)
        af[i] = *(const short8*)(As + (wm + 16 * i + lm) * 64 + ch);
#pragma unroll
      for (int j = 0; j < 4; j++)
        bf[j] = *(const short8*)(Bs + (wn + 16 * j + lm) * 64 + ch);
#pragma unroll
      for (int i = 0; i < 4; i++)
#pragma unroll
        for (int j = 0; j < 4; j++)
          acc[i][j] = __builtin_amdgcn_mfma_f32_16x16x32_bf16(af[i], bf[j], acc[i][j], 0, 0, 0);
    }
    __syncthreads();
  }

  float b1v[4], w2v[4];
#pragma unroll
  for (int j = 0; j < 4; j++) {
    int col = wn + 16 * j + lm;
    b1v[j] = bt1[t * 256 + col];
    w2v[j] = Wt2[t * 256 + col];
  }
  float* pt = (float*)As;
#pragma unroll
  for (int i = 0; i < 4; i++) {
#pragma unroll
    for (int v = 0; v < 4; v++) {
      float p = 0.f;
#pragma unroll
      for (int j = 0; j < 4; j++)
        p += fmaxf(acc[i][j][v] + b1v[j], 0.0f) * w2v[j];
      p += __shfl_xor(p, 1, 64);
      p += __shfl_xor(p, 2, 64);
      p += __shfl_xor(p, 4, 64);
      p += __shfl_xor(p, 8, 64);
      if (lm == 0) pt[(wm + 16 * i + lq * 4 + v) * 4 + (wave & 3)] = p;
    }
  }
  __syncthreads();
  if (tid < 128) {
    float s = pt[tid * 4] + pt[tid * 4 + 1] + pt[tid * 4 + 2] + pt[tid * 4 + 3] + bt2[t];
    out[(t << 14) + b0 + xbl * 128 + tid] = 1.f / (1.f + __expf(-s));
  }
}

extern "C" void kernel_launch(void* const* d_in, const int* in_sizes, int n_in,
                              void* d_out, int out_size, void* d_ws, size_t ws_size,
                              hipStream_t stream) {
  (void)in_sizes; (void)n_in; (void)out_size;
  const float* x   = (const float*)d_in[0];
  const float* We1 = (const float*)d_in[1];
  const float* be1 = (const float*)d_in[2];
  const float* We2 = (const float*)d_in[3];
  const float* be2 = (const float*)d_in[4];
  const float* Wg  = (const float*)d_in[5];
  const float* bg  = (const float*)d_in[6];
  const float* Wt1 = (const float*)d_in[7];
  const float* bt1 = (const float*)d_in[8];
  const float* Wt2 = (const float*)d_in[9];
  const float* bt2 = (const float*)d_in[10];
  float* out = (float*)d_out;

  char* ws = (char*)d_ws;
  unsigned short* xb   = (unsigned short*)(ws + 0);            // 33,554,432
  unsigned short* W1T  = (unsigned short*)(ws + 33554432);     //  8,388,608
  unsigned short* W2T  = (unsigned short*)(ws + 41943040);     //  4,194,304
  unsigned short* Wt1T = (unsigned short*)(ws + 46137344);     //    786,432
  float*          gts  = (float*)(ws + 46923776);              //  1,572,864
  float*          WgT  = (float*)(ws + 48496640);              //     98,304
  const size_t fixed = 48594944;

  // Adaptive chunk size: per-chunk buffers need Bc*11264 bytes (h1c+tic).
  size_t rem = ws_size > fixed ? ws_size - fixed : 0;
  int Bc = 16384;
  while (Bc > 512 && (size_t)Bc * 11264 > rem) Bc >>= 1;
  const int nc = 16384 / Bc;

  char* cb = ws + fixed;
  unsigned short* h1c = (unsigned short*)(cb);                      // Bc*8192 B
  unsigned short* tic = (unsigned short*)(cb + (size_t)Bc * 8192);  // Bc*3072 B

  // --- prologue ---
  prep_kernel<<<dim3(16, 32, 20), dim3(32, 8), 0, stream>>>(We1, We2, Wt1, Wg, W1T, W2T, Wt1T, WgT);
  gates_cvt_kernel<<<4096, 256, 0, stream>>>(x, WgT, bg, gts, xb);

  // --- per-chunk pipeline ---
  for (int c = 0; c < nc; c++) {
    const unsigned short* xbc = xb + (size_t)c * Bc * 1024;
    // h1c = relu(x_chunk @ We1 + be1)     M=Bc N=512 K=1024 per expert
    gemm_bt_relu<<<dim3(Bc / 128, 4, 8), 256, 0, stream>>>(
        xbc, 0L, 1024, W1T, 524288L, be1, 512, h1c, 512L, 4096, 1024);
    // tic = sum_e g * relu(h1c @ We2 + be2)   fused GEMM2+combine
    gemm2_combine_kernel<<<dim3(Bc / 128, 8), 256, 0, stream>>>(
        h1c, W2T, be2, gts, tic, c * Bc, Bc);
    // preds = sigmoid(relu(tic @ Wt1 + bt1) . Wt2 + bt2)
    tower_fused_kernel<<<3 * (Bc / 128), 512, 0, stream>>>(
        tic, Wt1T, bt1, Wt2, bt2, out, c * Bc, Bc);
  }
}

// Round 7
// 534.714 us; speedup vs baseline: 1.1062x; 1.1062x over previous
//
#include <hip/hip_runtime.h>

// MMoE: B=16384, D=1024, E=8, H=512, T=256, TASKS=3
// R2: 701 us. R3: 593 (coalesced gates). R4: 521 (XOR-swizzle LDS, conflicts
// 2.5e7->0, GEMM1 = 825 TF m97 plateau). R5: 498 (fused tail).
// R6 FAILED (591): gemm2+combine fusion was HBM-fetch-bound (FETCH 275 MB,
//   8x A re-read with BN=64 + x-major dispatch streaming 134 MB between
//   re-uses -> L3 eviction). Reverted.
// R7: R5 structure + grid swap (blockIdx.x = n-tile) so blocks sharing an
//   A-tile are temporally adjacent -> re-reads hit L2/L3. Bc capped 8192.

#define BM 128
#define BN 128
#define BK 64

typedef __attribute__((ext_vector_type(8))) short short8;
typedef __attribute__((ext_vector_type(4))) float floatx4;
typedef __attribute__((ext_vector_type(4))) unsigned short ushortx4;
typedef __attribute__((ext_vector_type(8))) unsigned short ushortx8;

__device__ __forceinline__ unsigned short f32_to_bf16(float f) {
  unsigned int u = __float_as_uint(f);
  u += 0x7fffu + ((u >> 16) & 1u);   // round-to-nearest-even (no NaNs in this net)
  return (unsigned short)(u >> 16);
}
__device__ __forceinline__ float bf16_to_f32(unsigned short h) {
  return __uint_as_float(((unsigned int)h) << 16);
}

__device__ __forceinline__ void async_cp16(const void* g, void* lds) {
  __builtin_amdgcn_global_load_lds(
      (const __attribute__((address_space(1))) void*)g,
      (__attribute__((address_space(3))) void*)lds, 16, 0, 0);
}

// ---------------- all weight prep in one kernel ----------------
__device__ __forceinline__ void transpose_slice(
    const float* __restrict__ in, unsigned short* __restrict__ out,
    int K, int N, float (*tile)[33]) {
  int n0 = blockIdx.x * 32, k0 = blockIdx.y * 32;
  for (int i = threadIdx.y; i < 32; i += 8)
    tile[i][threadIdx.x] = in[(size_t)(k0 + i) * N + n0 + threadIdx.x];
  __syncthreads();
  for (int i = threadIdx.y; i < 32; i += 8)
    out[(size_t)(n0 + i) * K + k0 + threadIdx.x] = f32_to_bf16(tile[threadIdx.x][i]);
}

__global__ void prep_kernel(const float* __restrict__ We1, const float* __restrict__ We2,
                            const float* __restrict__ Wt1, const float* __restrict__ Wg,
                            unsigned short* __restrict__ W1T, unsigned short* __restrict__ W2T,
                            unsigned short* __restrict__ Wt1T, float* __restrict__ WgT) {
  __shared__ float tile[32][33];
  int z = blockIdx.z;
  if (z < 8) {
    transpose_slice(We1 + (size_t)z * 524288, W1T + (size_t)z * 524288, 1024, 512, tile);
  } else if (z < 16) {
    if (blockIdx.y < 16)
      transpose_slice(We2 + (size_t)(z - 8) * 262144, W2T + (size_t)(z - 8) * 262144, 512, 512, tile);
  } else if (z < 19) {
    if (blockIdx.x < 8 && blockIdx.y < 16)
      transpose_slice(Wt1 + (size_t)(z - 16) * 131072, Wt1T + (size_t)(z - 16) * 131072, 512, 256, tile);
  } else {
    if (blockIdx.x < 16 && blockIdx.y < 6) {
      int idx = (blockIdx.y * 16 + blockIdx.x) * 256 + threadIdx.y * 32 + threadIdx.x;
      int t = idx >> 13, r = idx & 8191, e = r >> 10, d = r & 1023;
      WgT[idx] = Wg[t * 8192 + d * 8 + e];
    }
  }
}

// ---------------- gates + x->bf16 (fused; reads x once) ----------------
__global__ __launch_bounds__(256) void gates_cvt_kernel(
    const float* __restrict__ x, const float* __restrict__ WgT,
    const float* __restrict__ bg, float* __restrict__ gout,
    unsigned short* __restrict__ xb) {
  int wave = threadIdx.x >> 6, lane = threadIdx.x & 63;
  int b = blockIdx.x * 4 + wave;
  const float* xr = x + (size_t)b * 1024;
  float xv[16];
#pragma unroll
  for (int j = 0; j < 16; j++) xv[j] = xr[lane + 64 * j];
  unsigned short* xbr = xb + (size_t)b * 1024;
#pragma unroll
  for (int j = 0; j < 16; j++) xbr[lane + 64 * j] = f32_to_bf16(xv[j]);
  float mylogit = 0.f;
#pragma unroll
  for (int te = 0; te < 24; te++) {
    const float* w = WgT + te * 1024;
    float a = 0.f;
#pragma unroll
    for (int j = 0; j < 16; j++) a += xv[j] * w[lane + 64 * j];
#pragma unroll
    for (int off = 32; off > 0; off >>= 1) a += __shfl_xor(a, off, 64);
    if (lane == te) mylogit = a;
  }
  if (lane < 24) {
    int t = lane >> 3, e = lane & 7;
    float logit = mylogit + bg[lane];
    float m = logit;
    m = fmaxf(m, __shfl_xor(m, 4, 64));
    m = fmaxf(m, __shfl_xor(m, 2, 64));
    m = fmaxf(m, __shfl_xor(m, 1, 64));
    float ex = __expf(logit - m);
    float s = ex;
    s += __shfl_xor(s, 4, 64);
    s += __shfl_xor(s, 2, 64);
    s += __shfl_xor(s, 1, 64);
    gout[(size_t)t * 131072 + (size_t)b * 8 + e] = ex / s;
  }
}

// ---------------- m97-style bf16 GEMM: C = relu(A * B^T + bias), bf16 out ----------------
// blockIdx.x = n-tile (few), blockIdx.y = m-tile (many): blocks sharing an
// A-tile are temporally adjacent -> A re-reads hit L2/L3 (R6 lesson).
// LDS XOR-swizzled (R4).
__global__ __launch_bounds__(256) void gemm_bt_relu(
    const unsigned short* __restrict__ Abase, long aOffZ, int lda,
    const unsigned short* __restrict__ Bbase, long bOffZ,
    const float* __restrict__ biasBase, int biasOffZ,
    unsigned short* __restrict__ Cbase, long cOffZ, int ldc,
    int K) {
  __shared__ __align__(16) unsigned short As[BM * BK];
  __shared__ __align__(16) unsigned short Bs[BN * BK];
  const int tid = threadIdx.x;
  const int z = blockIdx.z;
  const unsigned short* A = Abase + (size_t)aOffZ * z + (size_t)blockIdx.y * BM * lda;
  const unsigned short* Bt = Bbase + (size_t)bOffZ * z + (size_t)blockIdx.x * BN * K;
  const float* bias = biasBase + (size_t)biasOffZ * z + blockIdx.x * BN;
  unsigned short* C = Cbase + (size_t)cOffZ * z + (size_t)blockIdx.y * BM * ldc + blockIdx.x * BN;

  const int wave = tid >> 6, lane = tid & 63;
  const int wm = (wave >> 1) * 64, wn = (wave & 1) * 64;
  const int lm = lane & 15, lq = lane >> 4;
  const int sw = lm & 7;

  floatx4 acc[4][4] = {};

  const int sr = tid >> 3;
  const int sc = (((tid & 7) ^ (sr & 7)) << 3);

  for (int kt = 0; kt < K; kt += BK) {
#pragma unroll
    for (int i = 0; i < 4; i++)
      async_cp16(A + (size_t)(sr + 32 * i) * lda + kt + sc,
                 (char*)As + i * 4096 + tid * 16);
#pragma unroll
    for (int i = 0; i < 4; i++)
      async_cp16(Bt + (size_t)(sr + 32 * i) * K + kt + sc,
                 (char*)Bs + i * 4096 + tid * 16);
    __syncthreads();
#pragma unroll
    for (int ks = 0; ks < 2; ks++) {
      short8 af[4], bf[4];
      const int ch = ((ks * 4 + lq) ^ sw) << 3;
#pragma unroll
      for (int i = 0; i < 4; i++)
        af[i] = *(const short8*)(As + (wm + 16 * i + lm) * BK + ch);
#pragma unroll
      for (int j = 0; j < 4; j++)
        bf[j] = *(const short8*)(Bs + (wn + 16 * j + lm) * BK + ch);
#pragma unroll
      for (int i = 0; i < 4; i++)
#pragma unroll
        for (int j = 0; j < 4; j++)
          acc[i][j] = __builtin_amdgcn_mfma_f32_16x16x32_bf16(af[i], bf[j], acc[i][j], 0, 0, 0);
    }
    __syncthreads();
  }

#pragma unroll
  for (int i = 0; i < 4; i++) {
    const int row = wm + 16 * i + lq * 4;
#pragma unroll
    for (int j = 0; j < 4; j++) {
      const int col = wn + 16 * j + lm;
      const float bv = bias[col];
#pragma unroll
      for (int v = 0; v < 4; v++) {
        float val = fmaxf(acc[i][j][v] + bv, 0.0f);
        C[(size_t)(row + v) * ldc + col] = f32_to_bf16(val);
      }
    }
  }
}

// ---------------- combine: tic[t,bl,h] = sum_e gates[t,b0+bl,e] * eoc[bl,e,h] ----------------
__global__ void combine_kernel(const unsigned short* __restrict__ eo,
                               const float* __restrict__ gates,
                               unsigned short* __restrict__ ti,
                               int b0, int Bc) {
  int tid = blockIdx.x * 256 + threadIdx.x;
  int bl = tid >> 6;
  int hc = (tid & 63) << 3;
  float g[3][8];
#pragma unroll
  for (int t = 0; t < 3; t++) {
    const floatx4* gp = (const floatx4*)(gates + ((size_t)t * 16384 + b0 + bl) * 8);
    floatx4 g0 = gp[0], g1 = gp[1];
#pragma unroll
    for (int j = 0; j < 4; j++) { g[t][j] = g0[j]; g[t][4 + j] = g1[j]; }
  }
  float out[3][8] = {};
#pragma unroll
  for (int e = 0; e < 8; e++) {
    ushortx8 v = *(const ushortx8*)(eo + ((size_t)bl * 8 + e) * 512 + hc);
#pragma unroll
    for (int j = 0; j < 8; j++) {
      float f = bf16_to_f32(v[j]);
#pragma unroll
      for (int t = 0; t < 3; t++) out[t][j] += g[t][e] * f;
    }
  }
#pragma unroll
  for (int t = 0; t < 3; t++) {
    ushortx8 o;
#pragma unroll
    for (int j = 0; j < 8; j++) o[j] = f32_to_bf16(out[t][j]);
    *(ushortx8*)(ti + ((size_t)t * Bc + bl) * 512 + hc) = o;
  }
}

// ---------------- fused towers: preds = sigmoid(relu(tic @ Wt1 + bt1) . Wt2 + bt2) ----------------
__global__ __launch_bounds__(512) void tower_fused_kernel(
    const unsigned short* __restrict__ tic, const unsigned short* __restrict__ Wt1T,
    const float* __restrict__ bt1, const float* __restrict__ Wt2,
    const float* __restrict__ bt2, float* __restrict__ out,
    int b0, int Bc) {
  __shared__ __align__(16) unsigned short As[128 * 64];
  __shared__ __align__(16) unsigned short Bs[256 * 64];
  const int tid = threadIdx.x;
  const int mtiles = Bc >> 7;
  const int t = blockIdx.x / mtiles;
  const int xbl = blockIdx.x % mtiles;
  const unsigned short* A = tic + ((size_t)t * Bc + (size_t)xbl * 128) * 512;
  const unsigned short* Bt = Wt1T + (size_t)t * 131072;

  const int wave = tid >> 6, lane = tid & 63;
  const int wm = (wave >> 2) * 64, wn = (wave & 3) * 64;
  const int lm = lane & 15, lq = lane >> 4;
  const int sw = lm & 7;

  floatx4 acc[4][4] = {};

  const int sr = tid >> 3;
  const int sc = (((tid & 7) ^ (sr & 7)) << 3);

  for (int kt = 0; kt < 512; kt += 64) {
#pragma unroll
    for (int i = 0; i < 2; i++)
      async_cp16(A + (size_t)(sr + 64 * i) * 512 + kt + sc,
                 (char*)As + i * 8192 + tid * 16);
#pragma unroll
    for (int i = 0; i < 4; i++)
      async_cp16(Bt + (size_t)(sr + 64 * i) * 512 + kt + sc,
                 (char*)Bs + i * 8192 + tid * 16);
    __syncthreads();
#pragma unroll
    for (int ks = 0; ks < 2; ks++) {
      short8 af[4], bf[4];
      const int ch = ((ks * 4 + lq) ^ sw) << 3;
#pragma unroll
      for (int i = 0; i < 4; i++)
        af[i] = *(const short8*)(As + (wm + 16 * i + lm) * 64 + ch);
#pragma unroll
      for (int j = 0; j < 4; j++)
        bf[j] = *(const short8*)(Bs + (wn + 16 * j + lm) * 64 + ch);
#pragma unroll
      for (int i = 0; i < 4; i++)
#pragma unroll
        for (int j = 0; j < 4; j++)
          acc[i][j] = __builtin_amdgcn_mfma_f32_16x16x32_bf16(af[i], bf[j], acc[i][j], 0, 0, 0);
    }
    __syncthreads();
  }

  float b1v[4], w2v[4];
#pragma unroll
  for (int j = 0; j < 4; j++) {
    int col = wn + 16 * j + lm;
    b1v[j] = bt1[t * 256 + col];
    w2v[j] = Wt2[t * 256 + col];
  }
  float* pt = (float*)As;
#pragma unroll
  for (int i = 0; i < 4; i++) {
#pragma unroll
    for (int v = 0; v < 4; v++) {
      float p = 0.f;
#pragma unroll
      for (int j = 0; j < 4; j++)
        p += fmaxf(acc[i][j][v] + b1v[j], 0.0f) * w2v[j];
      p += __shfl_xor(p, 1, 64);
      p += __shfl_xor(p, 2, 64);
      p += __shfl_xor(p, 4, 64);
      p += __shfl_xor(p, 8, 64);
      if (lm == 0) pt[(wm + 16 * i + lq * 4 + v) * 4 + (wave & 3)] = p;
    }
  }
  __syncthreads();
  if (tid < 128) {
    float s = pt[tid * 4] + pt[tid * 4 + 1] + pt[tid * 4 + 2] + pt[tid * 4 + 3] + bt2[t];
    out[(t << 14) + b0 + xbl * 128 + tid] = 1.f / (1.f + __expf(-s));
  }
}

extern "C" void kernel_launch(void* const* d_in, const int* in_sizes, int n_in,
                              void* d_out, int out_size, void* d_ws, size_t ws_size,
                              hipStream_t stream) {
  (void)in_sizes; (void)n_in; (void)out_size;
  const float* x   = (const float*)d_in[0];
  const float* We1 = (const float*)d_in[1];
  const float* be1 = (const float*)d_in[2];
  const float* We2 = (const float*)d_in[3];
  const float* be2 = (const float*)d_in[4];
  const float* Wg  = (const float*)d_in[5];
  const float* bg  = (const float*)d_in[6];
  const float* Wt1 = (const float*)d_in[7];
  const float* bt1 = (const float*)d_in[8];
  const float* Wt2 = (const float*)d_in[9];
  const float* bt2 = (const float*)d_in[10];
  float* out = (float*)d_out;

  char* ws = (char*)d_ws;
  unsigned short* xb   = (unsigned short*)(ws + 0);            // 33,554,432
  unsigned short* W1T  = (unsigned short*)(ws + 33554432);     //  8,388,608
  unsigned short* W2T  = (unsigned short*)(ws + 41943040);     //  4,194,304
  unsigned short* Wt1T = (unsigned short*)(ws + 46137344);     //    786,432
  float*          gts  = (float*)(ws + 46923776);              //  1,572,864
  float*          WgT  = (float*)(ws + 48496640);              //     98,304
  const size_t fixed = 48594944;

  // Per-chunk buffers need Bc*19456 bytes (h1c+eoc+tic). Cap Bc at 8192 so
  // h1c/eoc (67 MB) stay L3-resident for GEMM2/combine re-reads.
  size_t rem = ws_size > fixed ? ws_size - fixed : 0;
  int Bc = 8192;
  while (Bc > 512 && (size_t)Bc * 19456 > rem) Bc >>= 1;
  const int nc = 16384 / Bc;

  char* cb = ws + fixed;
  unsigned short* h1c = (unsigned short*)(cb);                      // Bc*8192 B
  unsigned short* eoc = (unsigned short*)(cb + (size_t)Bc * 8192);  // Bc*8192 B
  unsigned short* tic = (unsigned short*)(cb + (size_t)Bc * 16384); // Bc*3072 B

  // --- prologue ---
  prep_kernel<<<dim3(16, 32, 20), dim3(32, 8), 0, stream>>>(We1, We2, Wt1, Wg, W1T, W2T, Wt1T, WgT);
  gates_cvt_kernel<<<4096, 256, 0, stream>>>(x, WgT, bg, gts, xb);

  // --- per-chunk pipeline ---
  for (int c = 0; c < nc; c++) {
    const unsigned short* xbc = xb + (size_t)c * Bc * 1024;
    // h1c = relu(x_chunk @ We1 + be1)     M=Bc N=512 K=1024 per expert
    gemm_bt_relu<<<dim3(4, Bc / 128, 8), 256, 0, stream>>>(
        xbc, 0L, 1024, W1T, 524288L, be1, 512, h1c, 512L, 4096, 1024);
    // eoc = relu(h1c @ We2 + be2)         M=Bc N=512 K=512 per expert
    gemm_bt_relu<<<dim3(4, Bc / 128, 8), 256, 0, stream>>>(
        h1c, 512L, 4096, W2T, 262144L, be2, 512, eoc, 512L, 4096, 512);
    // tic[t,bl,:] = sum_e g * eoc
    combine_kernel<<<Bc / 4, 256, 0, stream>>>(eoc, gts, tic, c * Bc, Bc);
    // preds = sigmoid(relu(tic @ Wt1 + bt1) . Wt2 + bt2)
    tower_fused_kernel<<<3 * (Bc / 128), 512, 0, stream>>>(
        tic, Wt1T, bt1, Wt2, bt2, out, c * Bc, Bc);
  }
}

// Round 8
// 508.364 us; speedup vs baseline: 1.1636x; 1.0518x over previous
//
#include <hip/hip_runtime.h>

// MMoE: B=16384, D=1024, E=8, H=512, T=256, TASKS=3
// R2: 701 us. R3: 593 (coalesced gates). R4: 521 (XOR-swizzle LDS, conflicts
// 2.5e7->0, GEMM1 = 825 TF m97 plateau). R5: 498 (fused tail).
// R6 FAILED (591): gemm2+combine fusion HBM-fetch-bound (8x A re-read).
// R7 FAILED (534): n-fastest grid pessimized the EXPERT-axis A reuse
//   (FETCH 58->134 MB: 8 experts re-sweep the same 16 MB A through L2).
//   R5's m-fastest order is correct for this GEMM. Reverted.
// R8: R5 exact + tower 64-row tiles (192 blocks@512thr -> 384@256thr;
//   0.75 -> 1.5 blocks/CU during the tower phase).

#define BM 128
#define BN 128
#define BK 64

typedef __attribute__((ext_vector_type(8))) short short8;
typedef __attribute__((ext_vector_type(4))) float floatx4;
typedef __attribute__((ext_vector_type(4))) unsigned short ushortx4;
typedef __attribute__((ext_vector_type(8))) unsigned short ushortx8;

__device__ __forceinline__ unsigned short f32_to_bf16(float f) {
  unsigned int u = __float_as_uint(f);
  u += 0x7fffu + ((u >> 16) & 1u);   // round-to-nearest-even (no NaNs in this net)
  return (unsigned short)(u >> 16);
}
__device__ __forceinline__ float bf16_to_f32(unsigned short h) {
  return __uint_as_float(((unsigned int)h) << 16);
}

__device__ __forceinline__ void async_cp16(const void* g, void* lds) {
  __builtin_amdgcn_global_load_lds(
      (const __attribute__((address_space(1))) void*)g,
      (__attribute__((address_space(3))) void*)lds, 16, 0, 0);
}

// ---------------- all weight prep in one kernel ----------------
__device__ __forceinline__ void transpose_slice(
    const float* __restrict__ in, unsigned short* __restrict__ out,
    int K, int N, float (*tile)[33]) {
  int n0 = blockIdx.x * 32, k0 = blockIdx.y * 32;
  for (int i = threadIdx.y; i < 32; i += 8)
    tile[i][threadIdx.x] = in[(size_t)(k0 + i) * N + n0 + threadIdx.x];
  __syncthreads();
  for (int i = threadIdx.y; i < 32; i += 8)
    out[(size_t)(n0 + i) * K + k0 + threadIdx.x] = f32_to_bf16(tile[threadIdx.x][i]);
}

__global__ void prep_kernel(const float* __restrict__ We1, const float* __restrict__ We2,
                            const float* __restrict__ Wt1, const float* __restrict__ Wg,
                            unsigned short* __restrict__ W1T, unsigned short* __restrict__ W2T,
                            unsigned short* __restrict__ Wt1T, float* __restrict__ WgT) {
  __shared__ float tile[32][33];
  int z = blockIdx.z;
  if (z < 8) {
    transpose_slice(We1 + (size_t)z * 524288, W1T + (size_t)z * 524288, 1024, 512, tile);
  } else if (z < 16) {
    if (blockIdx.y < 16)
      transpose_slice(We2 + (size_t)(z - 8) * 262144, W2T + (size_t)(z - 8) * 262144, 512, 512, tile);
  } else if (z < 19) {
    if (blockIdx.x < 8 && blockIdx.y < 16)
      transpose_slice(Wt1 + (size_t)(z - 16) * 131072, Wt1T + (size_t)(z - 16) * 131072, 512, 256, tile);
  } else {
    if (blockIdx.x < 16 && blockIdx.y < 6) {
      int idx = (blockIdx.y * 16 + blockIdx.x) * 256 + threadIdx.y * 32 + threadIdx.x;
      int t = idx >> 13, r = idx & 8191, e = r >> 10, d = r & 1023;
      WgT[idx] = Wg[t * 8192 + d * 8 + e];
    }
  }
}

// ---------------- gates + x->bf16 (fused; reads x once) ----------------
__global__ __launch_bounds__(256) void gates_cvt_kernel(
    const float* __restrict__ x, const float* __restrict__ WgT,
    const float* __restrict__ bg, float* __restrict__ gout,
    unsigned short* __restrict__ xb) {
  int wave = threadIdx.x >> 6, lane = threadIdx.x & 63;
  int b = blockIdx.x * 4 + wave;
  const float* xr = x + (size_t)b * 1024;
  float xv[16];
#pragma unroll
  for (int j = 0; j < 16; j++) xv[j] = xr[lane + 64 * j];
  unsigned short* xbr = xb + (size_t)b * 1024;
#pragma unroll
  for (int j = 0; j < 16; j++) xbr[lane + 64 * j] = f32_to_bf16(xv[j]);
  float mylogit = 0.f;
#pragma unroll
  for (int te = 0; te < 24; te++) {
    const float* w = WgT + te * 1024;
    float a = 0.f;
#pragma unroll
    for (int j = 0; j < 16; j++) a += xv[j] * w[lane + 64 * j];
#pragma unroll
    for (int off = 32; off > 0; off >>= 1) a += __shfl_xor(a, off, 64);
    if (lane == te) mylogit = a;
  }
  if (lane < 24) {
    int t = lane >> 3, e = lane & 7;
    float logit = mylogit + bg[lane];
    float m = logit;
    m = fmaxf(m, __shfl_xor(m, 4, 64));
    m = fmaxf(m, __shfl_xor(m, 2, 64));
    m = fmaxf(m, __shfl_xor(m, 1, 64));
    float ex = __expf(logit - m);
    float s = ex;
    s += __shfl_xor(s, 4, 64);
    s += __shfl_xor(s, 2, 64);
    s += __shfl_xor(s, 1, 64);
    gout[(size_t)t * 131072 + (size_t)b * 8 + e] = ex / s;
  }
}

// ---------------- m97-style bf16 GEMM: C = relu(A * B^T + bias), bf16 out ----------------
// R5 grid order (blockIdx.x = m-tile fastest): keeps per-(n,z) B-tiles hot in
// L2 and lets L3 absorb A re-sweeps across n/z (R7 showed the alternative
// ordering pessimizes the expert-axis A reuse). LDS XOR-swizzled (R4).
__global__ __launch_bounds__(256) void gemm_bt_relu(
    const unsigned short* __restrict__ Abase, long aOffZ, int lda,
    const unsigned short* __restrict__ Bbase, long bOffZ,
    const float* __restrict__ biasBase, int biasOffZ,
    unsigned short* __restrict__ Cbase, long cOffZ, int ldc,
    int K) {
  __shared__ __align__(16) unsigned short As[BM * BK];
  __shared__ __align__(16) unsigned short Bs[BN * BK];
  const int tid = threadIdx.x;
  const int z = blockIdx.z;
  const unsigned short* A = Abase + (size_t)aOffZ * z + (size_t)blockIdx.x * BM * lda;
  const unsigned short* Bt = Bbase + (size_t)bOffZ * z + (size_t)blockIdx.y * BN * K;
  const float* bias = biasBase + (size_t)biasOffZ * z + blockIdx.y * BN;
  unsigned short* C = Cbase + (size_t)cOffZ * z + (size_t)blockIdx.x * BM * ldc + blockIdx.y * BN;

  const int wave = tid >> 6, lane = tid & 63;
  const int wm = (wave >> 1) * 64, wn = (wave & 1) * 64;
  const int lm = lane & 15, lq = lane >> 4;
  const int sw = lm & 7;

  floatx4 acc[4][4] = {};

  const int sr = tid >> 3;
  const int sc = (((tid & 7) ^ (sr & 7)) << 3);

  for (int kt = 0; kt < K; kt += BK) {
#pragma unroll
    for (int i = 0; i < 4; i++)
      async_cp16(A + (size_t)(sr + 32 * i) * lda + kt + sc,
                 (char*)As + i * 4096 + tid * 16);
#pragma unroll
    for (int i = 0; i < 4; i++)
      async_cp16(Bt + (size_t)(sr + 32 * i) * K + kt + sc,
                 (char*)Bs + i * 4096 + tid * 16);
    __syncthreads();
#pragma unroll
    for (int ks = 0; ks < 2; ks++) {
      short8 af[4], bf[4];
      const int ch = ((ks * 4 + lq) ^ sw) << 3;
#pragma unroll
      for (int i = 0; i < 4; i++)
        af[i] = *(const short8*)(As + (wm + 16 * i + lm) * BK + ch);
#pragma unroll
      for (int j = 0; j < 4; j++)
        bf[j] = *(const short8*)(Bs + (wn + 16 * j + lm) * BK + ch);
#pragma unroll
      for (int i = 0; i < 4; i++)
#pragma unroll
        for (int j = 0; j < 4; j++)
          acc[i][j] = __builtin_amdgcn_mfma_f32_16x16x32_bf16(af[i], bf[j], acc[i][j], 0, 0, 0);
    }
    __syncthreads();
  }

#pragma unroll
  for (int i = 0; i < 4; i++) {
    const int row = wm + 16 * i + lq * 4;
#pragma unroll
    for (int j = 0; j < 4; j++) {
      const int col = wn + 16 * j + lm;
      const float bv = bias[col];
#pragma unroll
      for (int v = 0; v < 4; v++) {
        float val = fmaxf(acc[i][j][v] + bv, 0.0f);
        C[(size_t)(row + v) * ldc + col] = f32_to_bf16(val);
      }
    }
  }
}

// ---------------- combine: tic[t,bl,h] = sum_e gates[t,b0+bl,e] * eoc[bl,e,h] ----------------
__global__ void combine_kernel(const unsigned short* __restrict__ eo,
                               const float* __restrict__ gates,
                               unsigned short* __restrict__ ti,
                               int b0, int Bc) {
  int tid = blockIdx.x * 256 + threadIdx.x;
  int bl = tid >> 6;
  int hc = (tid & 63) << 3;
  float g[3][8];
#pragma unroll
  for (int t = 0; t < 3; t++) {
    const floatx4* gp = (const floatx4*)(gates + ((size_t)t * 16384 + b0 + bl) * 8);
    floatx4 g0 = gp[0], g1 = gp[1];
#pragma unroll
    for (int j = 0; j < 4; j++) { g[t][j] = g0[j]; g[t][4 + j] = g1[j]; }
  }
  float out[3][8] = {};
#pragma unroll
  for (int e = 0; e < 8; e++) {
    ushortx8 v = *(const ushortx8*)(eo + ((size_t)bl * 8 + e) * 512 + hc);
#pragma unroll
    for (int j = 0; j < 8; j++) {
      float f = bf16_to_f32(v[j]);
#pragma unroll
      for (int t = 0; t < 3; t++) out[t][j] += g[t][e] * f;
    }
  }
#pragma unroll
  for (int t = 0; t < 3; t++) {
    ushortx8 o;
#pragma unroll
    for (int j = 0; j < 8; j++) o[j] = f32_to_bf16(out[t][j]);
    *(ushortx8*)(ti + ((size_t)t * Bc + bl) * 512 + hc) = o;
  }
}

// ---------------- fused towers: preds = sigmoid(relu(tic @ Wt1 + bt1) . Wt2 + bt2) ----------------
// 256 threads (4 waves), tile 64x256 (full tower width), K=512.
// Wave grid 1x4: wm=0, wn=wave*64. Same XOR-swizzled LDS. Grid 3*(Bc/64)
// blocks -> 1.5 blocks/CU at Bc=8192 (vs 0.75 for the 128-row version).
__global__ __launch_bounds__(256) void tower_fused_kernel(
    const unsigned short* __restrict__ tic, const unsigned short* __restrict__ Wt1T,
    const float* __restrict__ bt1, const float* __restrict__ Wt2,
    const float* __restrict__ bt2, float* __restrict__ out,
    int b0, int Bc) {
  __shared__ __align__(16) unsigned short As[64 * 64];    //  8 KB (reused for partials)
  __shared__ __align__(16) unsigned short Bs[256 * 64];   // 32 KB
  const int tid = threadIdx.x;
  const int mtiles = Bc >> 6;
  const int t = blockIdx.x / mtiles;
  const int xbl = blockIdx.x % mtiles;
  const unsigned short* A = tic + ((size_t)t * Bc + (size_t)xbl * 64) * 512;
  const unsigned short* Bt = Wt1T + (size_t)t * 131072;

  const int wave = tid >> 6, lane = tid & 63;
  const int wn = wave * 64;
  const int lm = lane & 15, lq = lane >> 4;
  const int sw = lm & 7;

  floatx4 acc[4][4] = {};

  const int sr = tid >> 3;                  // 0..31
  const int sc = (((tid & 7) ^ (sr & 7)) << 3);

  for (int kt = 0; kt < 512; kt += 64) {
#pragma unroll
    for (int i = 0; i < 2; i++)
      async_cp16(A + (size_t)(sr + 32 * i) * 512 + kt + sc,
                 (char*)As + i * 4096 + tid * 16);
#pragma unroll
    for (int i = 0; i < 8; i++)
      async_cp16(Bt + (size_t)(sr + 32 * i) * 512 + kt + sc,
                 (char*)Bs + i * 4096 + tid * 16);
    __syncthreads();
#pragma unroll
    for (int ks = 0; ks < 2; ks++) {
      short8 af[4], bf[4];
      const int ch = ((ks * 4 + lq) ^ sw) << 3;
#pragma unroll
      for (int i = 0; i < 4; i++)
        af[i] = *(const short8*)(As + (16 * i + lm) * 64 + ch);
#pragma unroll
      for (int j = 0; j < 4; j++)
        bf[j] = *(const short8*)(Bs + (wn + 16 * j + lm) * 64 + ch);
#pragma unroll
      for (int i = 0; i < 4; i++)
#pragma unroll
        for (int j = 0; j < 4; j++)
          acc[i][j] = __builtin_amdgcn_mfma_f32_16x16x32_bf16(af[i], bf[j], acc[i][j], 0, 0, 0);
    }
    __syncthreads();
  }

  float b1v[4], w2v[4];
#pragma unroll
  for (int j = 0; j < 4; j++) {
    int col = wn + 16 * j + lm;
    b1v[j] = bt1[t * 256 + col];
    w2v[j] = Wt2[t * 256 + col];
  }
  float* pt = (float*)As;   // 64 rows x 4 wn-groups
#pragma unroll
  for (int i = 0; i < 4; i++) {
#pragma unroll
    for (int v = 0; v < 4; v++) {
      float p = 0.f;
#pragma unroll
      for (int j = 0; j < 4; j++)
        p += fmaxf(acc[i][j][v] + b1v[j], 0.0f) * w2v[j];
      p += __shfl_xor(p, 1, 64);
      p += __shfl_xor(p, 2, 64);
      p += __shfl_xor(p, 4, 64);
      p += __shfl_xor(p, 8, 64);
      if (lm == 0) pt[(16 * i + lq * 4 + v) * 4 + wave] = p;
    }
  }
  __syncthreads();
  if (tid < 64) {
    float s = pt[tid * 4] + pt[tid * 4 + 1] + pt[tid * 4 + 2] + pt[tid * 4 + 3] + bt2[t];
    out[(t << 14) + b0 + xbl * 64 + tid] = 1.f / (1.f + __expf(-s));
  }
}

extern "C" void kernel_launch(void* const* d_in, const int* in_sizes, int n_in,
                              void* d_out, int out_size, void* d_ws, size_t ws_size,
                              hipStream_t stream) {
  (void)in_sizes; (void)n_in; (void)out_size;
  const float* x   = (const float*)d_in[0];
  const float* We1 = (const float*)d_in[1];
  const float* be1 = (const float*)d_in[2];
  const float* We2 = (const float*)d_in[3];
  const float* be2 = (const float*)d_in[4];
  const float* Wg  = (const float*)d_in[5];
  const float* bg  = (const float*)d_in[6];
  const float* Wt1 = (const float*)d_in[7];
  const float* bt1 = (const float*)d_in[8];
  const float* Wt2 = (const float*)d_in[9];
  const float* bt2 = (const float*)d_in[10];
  float* out = (float*)d_out;

  char* ws = (char*)d_ws;
  unsigned short* xb   = (unsigned short*)(ws + 0);            // 33,554,432
  unsigned short* W1T  = (unsigned short*)(ws + 33554432);     //  8,388,608
  unsigned short* W2T  = (unsigned short*)(ws + 41943040);     //  4,194,304
  unsigned short* Wt1T = (unsigned short*)(ws + 46137344);     //    786,432
  float*          gts  = (float*)(ws + 46923776);              //  1,572,864
  float*          WgT  = (float*)(ws + 48496640);              //     98,304
  const size_t fixed = 48594944;

  // Per-chunk buffers need Bc*19456 bytes (h1c+eoc+tic). Cap Bc at 8192 so
  // h1c/eoc (67 MB) stay L3-resident for GEMM2/combine re-reads.
  size_t rem = ws_size > fixed ? ws_size - fixed : 0;
  int Bc = 8192;
  while (Bc > 512 && (size_t)Bc * 19456 > rem) Bc >>= 1;
  const int nc = 16384 / Bc;

  char* cb = ws + fixed;
  unsigned short* h1c = (unsigned short*)(cb);                      // Bc*8192 B
  unsigned short* eoc = (unsigned short*)(cb + (size_t)Bc * 8192);  // Bc*8192 B
  unsigned short* tic = (unsigned short*)(cb + (size_t)Bc * 16384); // Bc*3072 B

  // --- prologue ---
  prep_kernel<<<dim3(16, 32, 20), dim3(32, 8), 0, stream>>>(We1, We2, Wt1, Wg, W1T, W2T, Wt1T, WgT);
  gates_cvt_kernel<<<4096, 256, 0, stream>>>(x, WgT, bg, gts, xb);

  // --- per-chunk pipeline ---
  for (int c = 0; c < nc; c++) {
    const unsigned short* xbc = xb + (size_t)c * Bc * 1024;
    // h1c = relu(x_chunk @ We1 + be1)     M=Bc N=512 K=1024 per expert
    gemm_bt_relu<<<dim3(Bc / 128, 4, 8), 256, 0, stream>>>(
        xbc, 0L, 1024, W1T, 524288L, be1, 512, h1c, 512L, 4096, 1024);
    // eoc = relu(h1c @ We2 + be2)         M=Bc N=512 K=512 per expert
    gemm_bt_relu<<<dim3(Bc / 128, 4, 8), 256, 0, stream>>>(
        h1c, 512L, 4096, W2T, 262144L, be2, 512, eoc, 512L, 4096, 512);
    // tic[t,bl,:] = sum_e g * eoc
    combine_kernel<<<Bc / 4, 256, 0, stream>>>(eoc, gts, tic, c * Bc, Bc);
    // preds = sigmoid(relu(tic @ Wt1 + bt1) . Wt2 + bt2)
    tower_fused_kernel<<<3 * (Bc / 64), 256, 0, stream>>>(
        tic, Wt1T, bt1, Wt2, bt2, out, c * Bc, Bc);
  }
}